// Round 1
// 966.641 us; speedup vs baseline: 1.0036x; 1.0036x over previous
//
#include <hip/hip_runtime.h>

#define N_   64
#define C4_  64
#define V_   25
#define T_   128
#define K_   3
#define OC_  192   // C4_*K_

// ---------------- K1: acc + depthwise temporal conv (5-tap, same pad) -------
// 8 rows (n,c,v) per block, 256 threads, float4 traffic through LDS halo rows.
__global__ __launch_bounds__(256)
void k1_acc_conv(const float* __restrict__ x, const float* __restrict__ out,
                 const float* __restrict__ conv_w, const float* __restrict__ conv_b,
                 float* __restrict__ s, int branch) {
    __shared__ float row[8][132];
    int tid = threadIdx.x;
    int r = tid >> 5;        // row within block, 0..7
    int q = tid & 31;        // t-quad, 0..31
    int grow = blockIdx.x * 8 + r;          // global row in [0, 64*64*25)
    int v  = grow % V_;
    int nc = grow / V_;
    int c  = nc % C4_;
    int n  = nc / C4_;

    const float4* xp = (const float4*)(x + ((size_t)(n * 256 + branch * C4_ + c) * V_ + v) * T_);
    float4 a = xp[q];
    if (branch > 0) {
        const float4* zp = (const float4*)(out + ((size_t)(n * 256 + (branch - 1) * C4_ + c) * V_ + v) * T_);
        float4 b = zp[q];
        a.x += b.x; a.y += b.y; a.z += b.z; a.w += b.w;
    }
    float* rw = &row[r][2 + q * 4];
    rw[0] = a.x; rw[1] = a.y; rw[2] = a.z; rw[3] = a.w;
    if (q == 0)  { row[r][0]   = 0.f; row[r][1]   = 0.f; }
    if (q == 31) { row[r][130] = 0.f; row[r][131] = 0.f; }
    __syncthreads();

    const float* wp = conv_w + (branch * C4_ + c) * 5;
    float w0 = wp[0], w1 = wp[1], w2 = wp[2], w3 = wp[3], w4 = wp[4];
    float b0 = conv_b[branch * C4_ + c];
    // row[r] base is 528B (16B-aligned); q*4 floats = 16B-aligned -> b128 reads
    const float4* rp4 = (const float4*)&row[r][q * 4];
    float4 f0 = rp4[0], f1 = rp4[1];
    float e0 = f0.x, e1 = f0.y, e2 = f0.z, e3 = f0.w;
    float e4 = f1.x, e5 = f1.y, e6 = f1.z, e7 = f1.w;
    float4 o4;
    o4.x = b0 + w0*e0 + w1*e1 + w2*e2 + w3*e3 + w4*e4;
    o4.y = b0 + w0*e1 + w1*e2 + w2*e3 + w3*e4 + w4*e5;
    o4.z = b0 + w0*e2 + w1*e3 + w2*e4 + w3*e5 + w4*e6;
    o4.w = b0 + w0*e3 + w1*e4 + w2*e5 + w3*e6 + w4*e7;
    float4* sp = (float4*)(s + ((size_t)(n * C4_ + c) * V_ + v) * T_);
    sp[q] = o4;
}

// ---------------- K23: fused per-node 1x1 conv + adjacency + BN + LeakyReLU -
// One wave per output channel c (wave-uniform -> W loads are scalar s_loads).
// Lane owns a t-pair (float2). acc[v] = 25 x float2 in VGPRs (no spill).
// Grid 1024 blocks (64 n x 16 cgroups), XCD-bijective swizzle: all 16 blocks
// of an n land on XCD n%8 so s[n] (819KB) is HBM-fetched once per n.
__global__ __launch_bounds__(256)
void k23(const float* __restrict__ s, const float* __restrict__ gW,
         const float* __restrict__ A,
         const float* __restrict__ bng, const float* __restrict__ bnb,
         const float* __restrict__ bnm, const float* __restrict__ bnv,
         float* __restrict__ out, int branch) {
    int bid  = blockIdx.x;
    int e    = bid & 7;            // XCD (dispatch round-robin heuristic)
    int slot = bid >> 3;           // 0..127
    int n    = e + 8 * (slot >> 4);  // 8 n per XCD
    int cg   = slot & 15;            // 16 c-groups of 4
    int wave = threadIdx.x >> 6;
    int lane = threadIdx.x & 63;
    int c    = __builtin_amdgcn_readfirstlane(cg * 4 + wave);  // uniform per wave
    int t0   = lane * 2;

    float2 acc[V_];
    #pragma unroll
    for (int v = 0; v < V_; ++v) { acc[v].x = 0.f; acc[v].y = 0.f; }

    const float* sp = s + (size_t)n * (C4_ * V_ * T_) + t0;

    for (int w = 0; w < V_; ++w) {
        // W rows o = c*3 .. c*3+2, contiguous in cin; scalar (SGPR) address
        const float* Wb = gW + (((size_t)branch * V_ + w) * OC_ + c * 3) * C4_;
        const float* srow = sp + (size_t)w * T_;
        float y0x = 0.f, y0y = 0.f, y1x = 0.f, y1y = 0.f, y2x = 0.f, y2y = 0.f;
        #pragma unroll 8
        for (int cin = 0; cin < C4_; ++cin) {
            float2 sv = *(const float2*)(srow + (size_t)cin * (V_ * T_));
            float w0 = Wb[cin];
            float w1 = Wb[C4_ + cin];
            float w2 = Wb[2 * C4_ + cin];
            y0x += w0 * sv.x; y0y += w0 * sv.y;
            y1x += w1 * sv.x; y1y += w1 * sv.y;
            y2x += w2 * sv.x; y2y += w2 * sv.y;
        }
        const float* A0 = A + (0 * V_ + w) * V_;
        const float* A1 = A + (1 * V_ + w) * V_;
        const float* A2 = A + (2 * V_ + w) * V_;
        #pragma unroll
        for (int v = 0; v < V_; ++v) {
            float a0 = A0[v], a1 = A1[v], a2 = A2[v];   // uniform -> s_load
            acc[v].x += a0 * y0x + a1 * y1x + a2 * y2x;
            acc[v].y += a0 * y0y + a1 * y1y + a2 * y2y;
        }
    }

    float g  = bng[branch * C4_ + c];
    float be = bnb[branch * C4_ + c];
    float mu = bnm[branch * C4_ + c];
    float va = bnv[branch * C4_ + c];
    float sc = g * rsqrtf(va + 1e-5f);
    float* op = out + ((size_t)(n * 256 + branch * C4_ + c) * V_) * T_ + t0;
    #pragma unroll
    for (int v = 0; v < V_; ++v) {
        float zx = (acc[v].x - mu) * sc + be;
        float zy = (acc[v].y - mu) * sc + be;
        zx = zx > 0.f ? zx : 0.2f * zx;
        zy = zy > 0.f ? zy : 0.2f * zy;
        float2 o2; o2.x = zx; o2.y = zy;
        *(float2*)(op + (size_t)v * T_) = o2;
    }
}

// ---------------- K4: passthrough split[3] -> out channels 192..255 ---------
__global__ __launch_bounds__(256)
void k4_copy(const float* __restrict__ x, float* __restrict__ out) {
    int i = blockIdx.x * blockDim.x + threadIdx.x;   // 0 .. 3,276,799
    int n = i / 51200;
    int j = i % 51200;
    const float4* src = (const float4*)(x + (size_t)(n * 256 + 192) * (V_ * T_));
    float4* dst = (float4*)(out + (size_t)(n * 256 + 192) * (V_ * T_));
    dst[j] = src[j];
}

extern "C" void kernel_launch(void* const* d_in, const int* in_sizes, int n_in,
                              void* d_out, int out_size, void* d_ws, size_t ws_size,
                              hipStream_t stream) {
    const float* x      = (const float*)d_in[0];
    const float* A      = (const float*)d_in[1];
    const float* conv_w = (const float*)d_in[2];
    const float* conv_b = (const float*)d_in[3];
    const float* gW     = (const float*)d_in[4];
    const float* bng    = (const float*)d_in[5];
    const float* bnb    = (const float*)d_in[6];
    const float* bnm    = (const float*)d_in[7];
    const float* bnv    = (const float*)d_in[8];
    float* out = (float*)d_out;

    float* s = (float*)d_ws;   // N*C4*V*T fp32 = 52,428,800 B

    for (int i = 0; i < 3; ++i) {
        hipLaunchKernelGGL(k1_acc_conv, dim3(N_ * C4_ * V_ / 8), dim3(256), 0, stream,
                           x, out, conv_w, conv_b, s, i);
        hipLaunchKernelGGL(k23, dim3(N_ * 16), dim3(256), 0, stream,
                           s, gW, A, bng, bnb, bnm, bnv, out, i);
    }
    hipLaunchKernelGGL(k4_copy, dim3(12800), dim3(256), 0, stream, x, out);
}

// Round 2
// 707.473 us; speedup vs baseline: 1.3713x; 1.3663x over previous
//
#include <hip/hip_runtime.h>

#define N_   64
#define C4_  64
#define V_   25
#define T_   128
#define K_   3
#define OC_  192   // C4_*K_

// ---------------- K1: acc + depthwise temporal conv (5-tap, same pad) -------
// No LDS: lane owns a t-quad; halo taps via __shfl within 32-lane row groups.
// XCD-bijective swizzle: rows of batch n land on XCD n%8 (matches k23).
__global__ __launch_bounds__(256)
void k1_acc_conv(const float* __restrict__ x, const float* __restrict__ out,
                 const float* __restrict__ conv_w, const float* __restrict__ conv_b,
                 float* __restrict__ s, int branch) {
    int bid  = blockIdx.x;            // 12800 blocks = 8 XCD * 8 n * 200
    int e    = bid & 7;
    int slot = bid >> 3;              // 0..1599
    int n    = e + 8 * (slot / 200);
    int inner = slot % 200;           // 200 blocks per n, 8 rows each
    int lane = threadIdx.x & 63;
    int wave = threadIdx.x >> 6;
    int rl   = wave * 2 + (lane >> 5);   // local row 0..7
    int q    = lane & 31;                // t-quad within row
    int rowv = inner * 8 + rl;           // 0..1599 within n  (= c*25 + v)
    int c = rowv / 25, v = rowv % 25;

    const float4* xp = (const float4*)(x + ((size_t)(n * 256 + branch * C4_ + c) * V_ + v) * T_);
    float4 a = xp[q];
    if (branch > 0) {
        const float4* zp = (const float4*)(out + ((size_t)(n * 256 + (branch - 1) * C4_ + c) * V_ + v) * T_);
        float4 b = zp[q];
        a.x += b.x; a.y += b.y; a.z += b.z; a.w += b.w;
    }
    // halo from neighbor quads (same 32-lane row group)
    float em2 = __shfl_up(a.z, 1, 32);
    float em1 = __shfl_up(a.w, 1, 32);
    float ep1 = __shfl_down(a.x, 1, 32);
    float ep2 = __shfl_down(a.y, 1, 32);
    if (q == 0)  { em2 = 0.f; em1 = 0.f; }
    if (q == 31) { ep1 = 0.f; ep2 = 0.f; }

    const float* wp = conv_w + (branch * C4_ + c) * 5;
    float w0 = wp[0], w1 = wp[1], w2 = wp[2], w3 = wp[3], w4 = wp[4];
    float b0 = conv_b[branch * C4_ + c];
    float4 o;
    o.x = b0 + w0*em2 + w1*em1 + w2*a.x + w3*a.y + w4*a.z;
    o.y = b0 + w0*em1 + w1*a.x + w2*a.y + w3*a.z + w4*a.w;
    o.z = b0 + w0*a.x + w1*a.y + w2*a.z + w3*a.w + w4*ep1;
    o.w = b0 + w0*a.y + w1*a.z + w2*a.w + w3*ep1 + w4*ep2;
    float4* sp = (float4*)(s + ((size_t)(n * C4_ + c) * V_ + v) * T_);
    sp[q] = o;
}

// ---------------- K23: fused per-node 1x1 conv + adjacency + BN + LeakyReLU -
// One wave per output channel c (W loads scalar). Lane owns a t-pair.
// NEW: s[n,:,w,:] staged into LDS in 32-cin half-tiles (16KB), double-buffered
// via global_load_lds prefetch -> L2 traffic /4, latency hidden.
__global__ __launch_bounds__(256, 4)
void k23(const float* __restrict__ s, const float* __restrict__ gW,
         const float* __restrict__ A,
         const float* __restrict__ bng, const float* __restrict__ bnb,
         const float* __restrict__ bnm, const float* __restrict__ bnv,
         float* __restrict__ out, int branch) {
    __shared__ float lds[8192];          // 2 x (32 cin x 128 t) = 32 KB
    int bid  = blockIdx.x;
    int e    = bid & 7;                  // XCD
    int slot = bid >> 3;                 // 0..127
    int n    = e + 8 * (slot >> 4);      // 8 n per XCD
    int cg   = slot & 15;
    int wave = threadIdx.x >> 6;
    int lane = threadIdx.x & 63;
    int c    = __builtin_amdgcn_readfirstlane(cg * 4 + wave);
    int t0   = lane * 2;

    const float* sbase = s + (size_t)n * (C4_ * V_ * T_);

    float2 acc[V_];
    #pragma unroll
    for (int v = 0; v < V_; ++v) { acc[v].x = 0.f; acc[v].y = 0.f; }

    // stage phase pp (w = pp>>1, cin-half = pp&1) into lds[dbase..dbase+4095]
    auto stage = [&](int pp, int dbase) {
        int w_ = pp >> 1, h_ = pp & 1;
        const float* g0 = sbase + (size_t)(h_ * 32) * (V_ * T_) + (size_t)w_ * T_;
        #pragma unroll
        for (int j = 0; j < 4; ++j) {
            int idx4 = (wave * 4 + j) * 64 + lane;     // float4 slot 0..1023
            int cl = idx4 >> 5, t4 = idx4 & 31;        // 32 float4 per cin row
            const float* gp = g0 + (size_t)cl * (V_ * T_) + t4 * 4;
            __builtin_amdgcn_global_load_lds(
                (const __attribute__((address_space(1))) void*)gp,
                (__attribute__((address_space(3))) void*)&lds[dbase + (wave * 4 + j) * 256],
                16, 0, 0);
        }
    };

    stage(0, 0);
    __syncthreads();

    float2 y0, y1, y2;
    for (int p = 0; p < 50; ++p) {
        int w_ = p >> 1, h = p & 1;
        int cur = (p & 1) * 4096;
        if (p < 49) stage(p + 1, cur ^ 4096);          // prefetch next half-tile

        const float* Wb = gW + (((size_t)branch * V_ + w_) * OC_ + c * 3) * C4_ + h * 32;
        const float* bp = lds + cur + t0;
        if (h == 0) { y0.x=y0.y=y1.x=y1.y=y2.x=y2.y=0.f; }
        #pragma unroll 8
        for (int cl = 0; cl < 32; ++cl) {
            float2 sv = *(const float2*)(bp + cl * T_);
            float a0 = Wb[cl], a1 = Wb[C4_ + cl], a2 = Wb[2 * C4_ + cl];  // s_load
            y0.x += a0 * sv.x; y0.y += a0 * sv.y;
            y1.x += a1 * sv.x; y1.y += a1 * sv.y;
            y2.x += a2 * sv.x; y2.y += a2 * sv.y;
        }
        if (h == 1) {
            const float* A0 = A + (0 * V_ + w_) * V_;
            const float* A1 = A + (1 * V_ + w_) * V_;
            const float* A2 = A + (2 * V_ + w_) * V_;
            #pragma unroll
            for (int v = 0; v < V_; ++v) {
                float a0 = A0[v], a1 = A1[v], a2 = A2[v];                 // s_load
                acc[v].x += a0 * y0.x + a1 * y1.x + a2 * y2.x;
                acc[v].y += a0 * y0.y + a1 * y1.y + a2 * y2.y;
            }
        }
        __syncthreads();
    }

    float g  = bng[branch * C4_ + c];
    float be = bnb[branch * C4_ + c];
    float mu = bnm[branch * C4_ + c];
    float va = bnv[branch * C4_ + c];
    float sc = g * rsqrtf(va + 1e-5f);
    float* op = out + ((size_t)(n * 256 + branch * C4_ + c) * V_) * T_ + t0;
    #pragma unroll
    for (int v = 0; v < V_; ++v) {
        float zx = (acc[v].x - mu) * sc + be;
        float zy = (acc[v].y - mu) * sc + be;
        zx = zx > 0.f ? zx : 0.2f * zx;
        zy = zy > 0.f ? zy : 0.2f * zy;
        float2 o2; o2.x = zx; o2.y = zy;
        *(float2*)(op + (size_t)v * T_) = o2;
    }
}

// ---------------- K4: passthrough split[3] -> out channels 192..255 ---------
__global__ __launch_bounds__(256)
void k4_copy(const float* __restrict__ x, float* __restrict__ out) {
    int i = blockIdx.x * blockDim.x + threadIdx.x;   // 0 .. 3,276,799
    int n = i / 51200;
    int j = i % 51200;
    const float4* src = (const float4*)(x + (size_t)(n * 256 + 192) * (V_ * T_));
    float4* dst = (float4*)(out + (size_t)(n * 256 + 192) * (V_ * T_));
    dst[j] = src[j];
}

extern "C" void kernel_launch(void* const* d_in, const int* in_sizes, int n_in,
                              void* d_out, int out_size, void* d_ws, size_t ws_size,
                              hipStream_t stream) {
    const float* x      = (const float*)d_in[0];
    const float* A      = (const float*)d_in[1];
    const float* conv_w = (const float*)d_in[2];
    const float* conv_b = (const float*)d_in[3];
    const float* gW     = (const float*)d_in[4];
    const float* bng    = (const float*)d_in[5];
    const float* bnb    = (const float*)d_in[6];
    const float* bnm    = (const float*)d_in[7];
    const float* bnv    = (const float*)d_in[8];
    float* out = (float*)d_out;

    float* s = (float*)d_ws;   // N*C4*V*T fp32 = 52,428,800 B

    for (int i = 0; i < 3; ++i) {
        hipLaunchKernelGGL(k1_acc_conv, dim3(12800), dim3(256), 0, stream,
                           x, out, conv_w, conv_b, s, i);
        hipLaunchKernelGGL(k23, dim3(N_ * 16), dim3(256), 0, stream,
                           s, gW, A, bng, bnb, bnm, bnv, out, i);
    }
    hipLaunchKernelGGL(k4_copy, dim3(12800), dim3(256), 0, stream, x, out);
}